// Round 9
// baseline (394.560 us; speedup 1.0000x reference)
//
#include <hip/hip_runtime.h>

// GCN_72988674228318: 2-layer GCN on MI355X. R9:
//  - agg1/agg2 XCD-sliced: blockIdx.x%NSLICE = column slice -> same-XCD L2
//    residency (slice working set 3.2 MB < 4 MB per-XCD L2); 4 lanes/node.
//  - gemm retiled 64x64 (RPT=4): LDS b128 per FMA 2.25 -> 1.5 cyc.

#define NN      50000
#define INC     128
#define HIDC    128
#define OUTC    64
#define NE      600000
#define NB      ((NN + 255) / 256)   // 196 scan blocks

// ---------------- Threefry-2x32, key = (0, 42); partitionable path ---------
__device__ __forceinline__ void tf_round(unsigned &x0, unsigned &x1, int r) {
  x0 += x1;
  x1 = (x1 << r) | (x1 >> (32 - r));
  x1 ^= x0;
}

__device__ __forceinline__ void threefry_0_42(unsigned &x0, unsigned &x1) {
  const unsigned ks0 = 0u, ks1 = 42u, ks2 = 0x1BD11BDAu ^ 42u;
  x0 += ks0; x1 += ks1;
  tf_round(x0,x1,13); tf_round(x0,x1,15); tf_round(x0,x1,26); tf_round(x0,x1, 6);
  x0 += ks1; x1 += ks2 + 1u;
  tf_round(x0,x1,17); tf_round(x0,x1,29); tf_round(x0,x1,16); tf_round(x0,x1,24);
  x0 += ks2; x1 += ks0 + 2u;
  tf_round(x0,x1,13); tf_round(x0,x1,15); tf_round(x0,x1,26); tf_round(x0,x1, 6);
  x0 += ks0; x1 += ks1 + 3u;
  tf_round(x0,x1,17); tf_round(x0,x1,29); tf_round(x0,x1,16); tf_round(x0,x1,24);
  x0 += ks1; x1 += ks2 + 4u;
  tf_round(x0,x1,13); tf_round(x0,x1,15); tf_round(x0,x1,26); tf_round(x0,x1, 6);
  x0 += ks2; x1 += ks0 + 5u;
}

__device__ __forceinline__ bool keep_bit(unsigned idx) {
  unsigned x0 = 0u, x1 = idx;
  threefry_0_42(x0, x1);
  return ((x0 ^ x1) & 0x80000000u) == 0u;
}

// ---------------- edge dtype detect -----------------------------------------
__global__ void detect_edge_dtype(const unsigned* __restrict__ w, int* __restrict__ flag) {
  __shared__ unsigned acc[256];
  unsigned v = 0;
  for (int i = threadIdx.x; i < 2048; i += 256) v |= w[2 * i + 1];
  acc[threadIdx.x] = v;
  __syncthreads();
  for (int s = 128; s > 0; s >>= 1) {
    if (threadIdx.x < s) acc[threadIdx.x] |= acc[threadIdx.x + s];
    __syncthreads();
  }
  if (threadIdx.x == 0) *flag = (acc[0] == 0u) ? 1 : 0;   // 1 => int64
}

__global__ void zero_int(int* p, int n) {
  int t = blockIdx.x * 256 + threadIdx.x;
  if (t < n) p[t] = 0;
}

// convert to int32 AND count in-degree (fused)
__global__ __launch_bounds__(256)
void convert_edges(const void* __restrict__ ei, const int* __restrict__ flag,
                   int* __restrict__ src, int* __restrict__ dst,
                   int* __restrict__ deg) {
  int t = blockIdx.x * 256 + threadIdx.x;
  if (t >= NE) return;
  int s, d;
  if (*flag) {
    const long long* e = (const long long*)ei;
    s = (int)e[t];
    d = (int)e[NE + t];
  } else {
    const int* e = (const int*)ei;
    s = e[t];
    d = e[NE + t];
  }
  src[t] = s;
  dst[t] = d;
  atomicAdd(&deg[d], 1);
}

// ---------------- hierarchical scan of deg -> offs/cursor -------------------
__global__ __launch_bounds__(256)
void scan_a(const int* __restrict__ deg, int* __restrict__ bsum,
            float* __restrict__ dinv) {
  __shared__ int red[256];
  int t = threadIdx.x, idx = blockIdx.x * 256 + t;
  int d = (idx < NN) ? deg[idx] : 0;
  if (idx < NN) dinv[idx] = 1.0f / sqrtf((float)(d + 1));
  red[t] = d;
  __syncthreads();
  for (int s = 128; s > 0; s >>= 1) {
    if (t < s) red[t] += red[t + s];
    __syncthreads();
  }
  if (t == 0) bsum[blockIdx.x] = red[0];
}

__global__ __launch_bounds__(256)
void scan_b(const int* __restrict__ bsum, int* __restrict__ boff,
            int* __restrict__ offs) {
  __shared__ int sums[256];
  int t = threadIdx.x;
  int v = (t < NB) ? bsum[t] : 0;
  sums[t] = v;
  __syncthreads();
  for (int off = 1; off < 256; off <<= 1) {
    int u = (t >= off) ? sums[t - off] : 0;
    __syncthreads();
    sums[t] += u;
    __syncthreads();
  }
  if (t < NB) boff[t] = sums[t] - v;
  if (t == 255) offs[NN] = sums[255];
}

__global__ __launch_bounds__(256)
void scan_c(const int* __restrict__ deg, const int* __restrict__ boff,
            int* __restrict__ offs, int* __restrict__ cursor) {
  __shared__ int sums[256];
  int t = threadIdx.x, idx = blockIdx.x * 256 + t;
  int d = (idx < NN) ? deg[idx] : 0;
  sums[t] = d;
  __syncthreads();
  for (int off = 1; off < 256; off <<= 1) {
    int u = (t >= off) ? sums[t - off] : 0;
    __syncthreads();
    sums[t] += u;
    __syncthreads();
  }
  if (idx < NN) {
    int o = boff[blockIdx.x] + sums[t] - d;
    offs[idx] = o;
    cursor[idx] = o;
  }
}

__global__ __launch_bounds__(256)
void bucket(const int* __restrict__ src, const int* __restrict__ dst,
            int* __restrict__ cursor, int* __restrict__ ssrc) {
  int t = blockIdx.x * 256 + threadIdx.x;
  if (t >= NE) return;
  int pos = atomicAdd(&cursor[dst[t]], 1);
  ssrc[pos] = src[t];
}

// ---------------- GEMM: A = (X @ W) * dinv[row], 64x64 tiles ----------------
// grid: (ceil(n/64), C/CT). 256 thr. LDS = K*CT*4 + 64*K*4 = 64 KB (K=128).
template<int K, int C, int CT>
__global__ __launch_bounds__(256, 3)
void gemm_scale(const float* __restrict__ X, const float* __restrict__ W,
                const float* __restrict__ dinv, float* __restrict__ A, int n) {
  __shared__ float ws[K * CT];
  __shared__ float xs[64 * K];
  const int tid = threadIdx.x;
  const int rowbase = blockIdx.x * 64;
  const int c0 = blockIdx.y * CT;

  for (int i = tid * 4; i < K * CT; i += 256 * 4) {
    int k = i / CT, c = i % CT;
    *(float4*)&ws[i] = *(const float4*)&W[(size_t)k * C + c0 + c];
  }
  for (int i = tid * 4; i < 64 * K; i += 256 * 4) {
    int r = i / K, k = i % K;
    int row = rowbase + r;
    float4 v = make_float4(0.f, 0.f, 0.f, 0.f);
    if (row < n) v = *(const float4*)&X[(size_t)row * K + k];
    *(float4*)&xs[i] = v;
  }
  __syncthreads();

  constexpr int CG  = CT / 4;          // 16
  constexpr int RPT = 64 * CG / 256;   // 4
  const int colq = tid % CG;
  const int rowq = tid / CG;           // 0..15

  float acc[RPT][4];
#pragma unroll
  for (int r = 0; r < RPT; r++)
#pragma unroll
    for (int c = 0; c < 4; c++) acc[r][c] = 0.f;

#pragma unroll 2
  for (int k0 = 0; k0 < K; k0 += 4) {
    float4 wv[4];
#pragma unroll
    for (int j = 0; j < 4; j++)
      wv[j] = *(float4*)&ws[(k0 + j) * CT + colq * 4];
#pragma unroll
    for (int r = 0; r < RPT; r++) {
      float4 xv = *(float4*)&xs[(rowq * RPT + r) * K + k0];
      acc[r][0] += xv.x*wv[0].x + xv.y*wv[1].x + xv.z*wv[2].x + xv.w*wv[3].x;
      acc[r][1] += xv.x*wv[0].y + xv.y*wv[1].y + xv.z*wv[2].y + xv.w*wv[3].y;
      acc[r][2] += xv.x*wv[0].z + xv.y*wv[1].z + xv.z*wv[2].z + xv.w*wv[3].z;
      acc[r][3] += xv.x*wv[0].w + xv.y*wv[1].w + xv.z*wv[2].w + xv.w*wv[3].w;
    }
  }

#pragma unroll
  for (int r = 0; r < RPT; r++) {
    int row = rowbase + rowq * RPT + r;
    if (row < n) {
      float s = dinv[row];
      *(float4*)&A[(size_t)row * C + c0 + colq * 4] =
        make_float4(acc[r][0]*s, acc[r][1]*s, acc[r][2]*s, acc[r][3]*s);
    }
  }
}

__device__ __forceinline__ void f4add(float4 &a, const float4 &b) {
  a.x += b.x; a.y += b.y; a.z += b.z; a.w += b.w;
}

// ---------------- agg1: XCD-sliced gather + bias/relu/dropout ---------------
// 8 slices x 16 cols. blockIdx.x % 8 = slice -> lands on one XCD (round-robin
// dispatch), so that XCD's L2 caches only its 3.2 MB column slice of A1.
// 4 lanes per node (float4 each), 64 nodes per 256-thread block.
__global__ __launch_bounds__(256)
void agg1(const float* __restrict__ A1, const int* __restrict__ offs,
          const int* __restrict__ ssrc, const float* __restrict__ dinv,
          const float* __restrict__ b1, float* __restrict__ H) {
  const int slice = blockIdx.x & 7;
  const int chunk = blockIdx.x >> 3;
  const int node  = chunk * 64 + (threadIdx.x >> 2);
  const int c     = threadIdx.x & 3;
  const int col4  = slice * 4 + c;            // float4 index within 32
  if (node >= NN) return;

  const float4* A4 = (const float4*)A1;
  float4 acc = A4[(size_t)node * 32 + col4];  // self-loop term
  int e = offs[node], end = offs[node + 1];
  for (; e + 3 < end; e += 4) {
    int s0 = ssrc[e], s1 = ssrc[e+1], s2 = ssrc[e+2], s3 = ssrc[e+3];
    float4 v0 = A4[(size_t)s0 * 32 + col4];
    float4 v1 = A4[(size_t)s1 * 32 + col4];
    float4 v2 = A4[(size_t)s2 * 32 + col4];
    float4 v3 = A4[(size_t)s3 * 32 + col4];
    f4add(v0, v1); f4add(v2, v3); f4add(v0, v2); f4add(acc, v0);
  }
  for (; e < end; e++)
    f4add(acc, A4[(size_t)ssrc[e] * 32 + col4]);

  float dv = dinv[node];
  float4 bb = ((const float4*)b1)[col4];
  float h0 = fmaxf(acc.x * dv + bb.x, 0.f);
  float h1 = fmaxf(acc.y * dv + bb.y, 0.f);
  float h2 = fmaxf(acc.z * dv + bb.z, 0.f);
  float h3 = fmaxf(acc.w * dv + bb.w, 0.f);
  unsigned base = (unsigned)node * HIDC + (unsigned)col4 * 4;
  float4 o;
  o.x = keep_bit(base)     ? 2.f * h0 : 0.f;
  o.y = keep_bit(base + 1) ? 2.f * h1 : 0.f;
  o.z = keep_bit(base + 2) ? 2.f * h2 : 0.f;
  o.w = keep_bit(base + 3) ? 2.f * h3 : 0.f;
  ((float4*)H)[(size_t)node * 32 + col4] = o;
}

// ---------------- agg2: XCD-sliced gather + bias -> d_out -------------------
// 4 slices x 16 cols (A2 row = 64 floats = 16 float4).
__global__ __launch_bounds__(256)
void agg2(const float* __restrict__ A2, const int* __restrict__ offs,
          const int* __restrict__ ssrc, const float* __restrict__ dinv,
          const float* __restrict__ b2, float* __restrict__ out) {
  const int slice = blockIdx.x & 3;
  const int chunk = blockIdx.x >> 2;
  const int node  = chunk * 64 + (threadIdx.x >> 2);
  const int c     = threadIdx.x & 3;
  const int col4  = slice * 4 + c;            // float4 index within 16
  if (node >= NN) return;

  const float4* A4 = (const float4*)A2;
  float4 acc = A4[(size_t)node * 16 + col4];
  int e = offs[node], end = offs[node + 1];
  for (; e + 3 < end; e += 4) {
    int s0 = ssrc[e], s1 = ssrc[e+1], s2 = ssrc[e+2], s3 = ssrc[e+3];
    float4 v0 = A4[(size_t)s0 * 16 + col4];
    float4 v1 = A4[(size_t)s1 * 16 + col4];
    float4 v2 = A4[(size_t)s2 * 16 + col4];
    float4 v3 = A4[(size_t)s3 * 16 + col4];
    f4add(v0, v1); f4add(v2, v3); f4add(v0, v2); f4add(acc, v0);
  }
  for (; e < end; e++)
    f4add(acc, A4[(size_t)ssrc[e] * 16 + col4]);

  float dv = dinv[node];
  float4 bb = ((const float4*)b2)[col4];
  ((float4*)out)[(size_t)node * 16 + col4] =
    make_float4(acc.x*dv + bb.x, acc.y*dv + bb.y, acc.z*dv + bb.z, acc.w*dv + bb.w);
}

// ---------------------------------------------------------------------------
extern "C" void kernel_launch(void* const* d_in, const int* in_sizes, int n_in,
                              void* d_out, int out_size, void* d_ws, size_t ws_size,
                              hipStream_t stream) {
  const float* x  = (const float*)d_in[0];
  const float* W1 = (const float*)d_in[1];
  const float* b1 = (const float*)d_in[2];
  const float* W2 = (const float*)d_in[3];
  const float* b2 = (const float*)d_in[4];
  const void*  ei = d_in[5];
  float* out = (float*)d_out;

  int*   flag   = (int*)d_ws;          // 64
  int*   src    = flag + 64;           // 600000
  int*   dst    = src + NE;            // 600000
  int*   deg    = dst + NE;            // 50048
  int*   offs   = deg + 50048;         // 50056
  int*   cursor = offs + 50056;        // 50048
  int*   ssrc   = cursor + 50048;      // 600000
  int*   bsum   = ssrc + NE;           // 256
  int*   boff   = bsum + 256;          // 256
  float* dinv   = (float*)(boff + 256);// 50048
  float* A1     = dinv + 50048;        // 6.4M
  float* H      = A1 + 6400000;        // 6.4M
  float* A2     = H + 6400000;         // 3.2M

  // 0. edges -> int32 (+ degree count fused)
  detect_edge_dtype<<<1, 256, 0, stream>>>((const unsigned*)ei, flag);
  zero_int<<<(NN + 255) / 256, 256, 0, stream>>>(deg, NN);
  convert_edges<<<(NE + 255) / 256, 256, 0, stream>>>(ei, flag, src, dst, deg);

  // 1. hierarchical scan -> offs/cursor (+ dinv fused)
  scan_a<<<NB, 256, 0, stream>>>(deg, bsum, dinv);
  scan_b<<<1, 256, 0, stream>>>(bsum, boff, offs);
  scan_c<<<NB, 256, 0, stream>>>(deg, boff, offs, cursor);
  bucket<<<(NE + 255) / 256, 256, 0, stream>>>(src, dst, cursor, ssrc);

  const int chunks = (NN + 63) / 64;   // 782

  // 2. layer 1
  gemm_scale<INC, HIDC, 64><<<dim3(chunks, HIDC / 64), 256, 0, stream>>>(x, W1, dinv, A1, NN);
  agg1<<<chunks * 8, 256, 0, stream>>>(A1, offs, ssrc, dinv, b1, H);

  // 3. layer 2
  gemm_scale<HIDC, OUTC, 64><<<dim3(chunks, 1), 256, 0, stream>>>(H, W2, dinv, A2, NN);
  agg2<<<chunks * 4, 256, 0, stream>>>(A2, offs, ssrc, dinv, b2, out);
}

// Round 10
// 264.621 us; speedup vs baseline: 1.4910x; 1.4910x over previous
//
#include <hip/hip_runtime.h>

// GCN_72988674228318: 2-layer GCN on MI355X. R10: revert R9's column slicing
// (2x line-split overfetch, FETCH 172->353 MB). Attack gather payload instead:
// A1/A2 staged as bf16 (gemm epilogue converts) -> half the gather bytes.
// Drop convert_edges (read edge_index directly in count_deg/bucket).

#define NN      50000
#define INC     128
#define HIDC    128
#define OUTC    64
#define NE      600000
#define NB      ((NN + 255) / 256)   // 196 scan blocks

typedef unsigned short bf16_t;

__device__ __forceinline__ unsigned short f2bf(float f) {
  unsigned u = __float_as_uint(f);
  u += 0x7fffu + ((u >> 16) & 1u);   // round to nearest even
  return (unsigned short)(u >> 16);
}

// ---------------- Threefry-2x32, key = (0, 42); partitionable path ---------
__device__ __forceinline__ void tf_round(unsigned &x0, unsigned &x1, int r) {
  x0 += x1;
  x1 = (x1 << r) | (x1 >> (32 - r));
  x1 ^= x0;
}

__device__ __forceinline__ void threefry_0_42(unsigned &x0, unsigned &x1) {
  const unsigned ks0 = 0u, ks1 = 42u, ks2 = 0x1BD11BDAu ^ 42u;
  x0 += ks0; x1 += ks1;
  tf_round(x0,x1,13); tf_round(x0,x1,15); tf_round(x0,x1,26); tf_round(x0,x1, 6);
  x0 += ks1; x1 += ks2 + 1u;
  tf_round(x0,x1,17); tf_round(x0,x1,29); tf_round(x0,x1,16); tf_round(x0,x1,24);
  x0 += ks2; x1 += ks0 + 2u;
  tf_round(x0,x1,13); tf_round(x0,x1,15); tf_round(x0,x1,26); tf_round(x0,x1, 6);
  x0 += ks0; x1 += ks1 + 3u;
  tf_round(x0,x1,17); tf_round(x0,x1,29); tf_round(x0,x1,16); tf_round(x0,x1,24);
  x0 += ks1; x1 += ks2 + 4u;
  tf_round(x0,x1,13); tf_round(x0,x1,15); tf_round(x0,x1,26); tf_round(x0,x1, 6);
  x0 += ks2; x1 += ks0 + 5u;
}

__device__ __forceinline__ bool keep_bit(unsigned idx) {
  unsigned x0 = 0u, x1 = idx;
  threefry_0_42(x0, x1);
  return ((x0 ^ x1) & 0x80000000u) == 0u;
}

// ---------------- edge dtype detect -----------------------------------------
__global__ void detect_edge_dtype(const unsigned* __restrict__ w, int* __restrict__ flag) {
  __shared__ unsigned acc[256];
  unsigned v = 0;
  for (int i = threadIdx.x; i < 2048; i += 256) v |= w[2 * i + 1];
  acc[threadIdx.x] = v;
  __syncthreads();
  for (int s = 128; s > 0; s >>= 1) {
    if (threadIdx.x < s) acc[threadIdx.x] |= acc[threadIdx.x + s];
    __syncthreads();
  }
  if (threadIdx.x == 0) *flag = (acc[0] == 0u) ? 1 : 0;   // 1 => int64
}

__global__ void zero_int(int* p, int n) {
  int t = blockIdx.x * 256 + threadIdx.x;
  if (t < n) p[t] = 0;
}

__global__ __launch_bounds__(256)
void count_deg_raw(const void* __restrict__ ei, const int* __restrict__ flag,
                   int* __restrict__ deg) {
  int t = blockIdx.x * 256 + threadIdx.x;
  if (t >= NE) return;
  int d = (*flag) ? (int)((const long long*)ei)[NE + t]
                  : ((const int*)ei)[NE + t];
  atomicAdd(&deg[d], 1);
}

// ---------------- hierarchical scan of deg -> offs/cursor -------------------
__global__ __launch_bounds__(256)
void scan_a(const int* __restrict__ deg, int* __restrict__ bsum,
            float* __restrict__ dinv) {
  __shared__ int red[256];
  int t = threadIdx.x, idx = blockIdx.x * 256 + t;
  int d = (idx < NN) ? deg[idx] : 0;
  if (idx < NN) dinv[idx] = 1.0f / sqrtf((float)(d + 1));
  red[t] = d;
  __syncthreads();
  for (int s = 128; s > 0; s >>= 1) {
    if (t < s) red[t] += red[t + s];
    __syncthreads();
  }
  if (t == 0) bsum[blockIdx.x] = red[0];
}

__global__ __launch_bounds__(256)
void scan_b(const int* __restrict__ bsum, int* __restrict__ boff,
            int* __restrict__ offs) {
  __shared__ int sums[256];
  int t = threadIdx.x;
  int v = (t < NB) ? bsum[t] : 0;
  sums[t] = v;
  __syncthreads();
  for (int off = 1; off < 256; off <<= 1) {
    int u = (t >= off) ? sums[t - off] : 0;
    __syncthreads();
    sums[t] += u;
    __syncthreads();
  }
  if (t < NB) boff[t] = sums[t] - v;
  if (t == 255) offs[NN] = sums[255];
}

__global__ __launch_bounds__(256)
void scan_c(const int* __restrict__ deg, const int* __restrict__ boff,
            int* __restrict__ offs, int* __restrict__ cursor) {
  __shared__ int sums[256];
  int t = threadIdx.x, idx = blockIdx.x * 256 + t;
  int d = (idx < NN) ? deg[idx] : 0;
  sums[t] = d;
  __syncthreads();
  for (int off = 1; off < 256; off <<= 1) {
    int u = (t >= off) ? sums[t - off] : 0;
    __syncthreads();
    sums[t] += u;
    __syncthreads();
  }
  if (idx < NN) {
    int o = boff[blockIdx.x] + sums[t] - d;
    offs[idx] = o;
    cursor[idx] = o;
  }
}

__global__ __launch_bounds__(256)
void bucket_raw(const void* __restrict__ ei, const int* __restrict__ flag,
                int* __restrict__ cursor, int* __restrict__ ssrc) {
  int t = blockIdx.x * 256 + threadIdx.x;
  if (t >= NE) return;
  int s, d;
  if (*flag) {
    s = (int)((const long long*)ei)[t];
    d = (int)((const long long*)ei)[NE + t];
  } else {
    s = ((const int*)ei)[t];
    d = ((const int*)ei)[NE + t];
  }
  int pos = atomicAdd(&cursor[d], 1);
  ssrc[pos] = s;
}

// ---------------- GEMM: Ab = bf16((X @ W) * dinv[row]), 32x64 panels --------
// grid: (ceil(n/32), C/64). LDS = 32 KB(W) + 16 KB(X) = 48 KB -> 3 blocks/CU.
template<int K, int C>
__global__ __launch_bounds__(256, 3)
void gemm_scale_bf(const float* __restrict__ X, const float* __restrict__ W,
                   const float* __restrict__ dinv, bf16_t* __restrict__ Ab, int n) {
  constexpr int CT = 64;
  __shared__ float ws[K * CT];
  __shared__ float xs[32 * K];
  const int tid = threadIdx.x;
  const int rowbase = blockIdx.x * 32;
  const int c0 = blockIdx.y * CT;

  for (int i = tid * 4; i < K * CT; i += 256 * 4) {
    int k = i / CT, c = i % CT;
    *(float4*)&ws[i] = *(const float4*)&W[(size_t)k * C + c0 + c];
  }
  for (int i = tid * 4; i < 32 * K; i += 256 * 4) {
    int r = i / K, k = i % K;
    int row = rowbase + r;
    float4 v = make_float4(0.f, 0.f, 0.f, 0.f);
    if (row < n) v = *(const float4*)&X[(size_t)row * K + k];
    *(float4*)&xs[i] = v;
  }
  __syncthreads();

  constexpr int CG  = CT / 4;          // 16
  constexpr int RPT = 32 * CG / 256;   // 2
  const int colq = tid % CG;
  const int rowq = tid / CG;

  float acc[RPT][4];
#pragma unroll
  for (int r = 0; r < RPT; r++)
#pragma unroll
    for (int c = 0; c < 4; c++) acc[r][c] = 0.f;

#pragma unroll 2
  for (int k0 = 0; k0 < K; k0 += 4) {
    float4 wv[4];
#pragma unroll
    for (int j = 0; j < 4; j++)
      wv[j] = *(float4*)&ws[(k0 + j) * CT + colq * 4];
#pragma unroll
    for (int r = 0; r < RPT; r++) {
      float4 xv = *(float4*)&xs[(rowq * RPT + r) * K + k0];
      acc[r][0] += xv.x*wv[0].x + xv.y*wv[1].x + xv.z*wv[2].x + xv.w*wv[3].x;
      acc[r][1] += xv.x*wv[0].y + xv.y*wv[1].y + xv.z*wv[2].y + xv.w*wv[3].y;
      acc[r][2] += xv.x*wv[0].z + xv.y*wv[1].z + xv.z*wv[2].z + xv.w*wv[3].z;
      acc[r][3] += xv.x*wv[0].w + xv.y*wv[1].w + xv.z*wv[2].w + xv.w*wv[3].w;
    }
  }

#pragma unroll
  for (int r = 0; r < RPT; r++) {
    int row = rowbase + rowq * RPT + r;
    if (row < n) {
      float s = dinv[row];
      ushort4 o;
      o.x = f2bf(acc[r][0] * s);
      o.y = f2bf(acc[r][1] * s);
      o.z = f2bf(acc[r][2] * s);
      o.w = f2bf(acc[r][3] * s);
      *(ushort4*)&Ab[(size_t)row * C + c0 + colq * 4] = o;
    }
  }
}

__device__ __forceinline__ void acc_u2(float4 &a, uint2 v) {
  a.x += __uint_as_float(v.x << 16);
  a.y += __uint_as_float(v.x & 0xffff0000u);
  a.z += __uint_as_float(v.y << 16);
  a.w += __uint_as_float(v.y & 0xffff0000u);
}

// ---------------- agg1: half-wave/node bf16 gather + bias/relu/dropout ------
// 32 lanes x uint2(4 bf16) = full 256 B row. H written fp32 for gemm2.
__global__ __launch_bounds__(256)
void agg1(const bf16_t* __restrict__ A1b, const int* __restrict__ offs,
          const int* __restrict__ ssrc, const float* __restrict__ dinv,
          const float* __restrict__ b1, float* __restrict__ H) {
  int node = (blockIdx.x * 256 + threadIdx.x) >> 5;
  int lane = threadIdx.x & 31;
  if (node >= NN) return;

  const uint2* A4 = (const uint2*)A1b;   // 4 bf16 per uint2; 32 per row
  float4 acc = make_float4(0.f, 0.f, 0.f, 0.f);
  acc_u2(acc, A4[(size_t)node * 32 + lane]);   // self-loop term
  int e = offs[node], end = offs[node + 1];
  for (; e + 3 < end; e += 4) {
    int s0 = ssrc[e], s1 = ssrc[e+1], s2 = ssrc[e+2], s3 = ssrc[e+3];
    uint2 v0 = A4[(size_t)s0 * 32 + lane];
    uint2 v1 = A4[(size_t)s1 * 32 + lane];
    uint2 v2 = A4[(size_t)s2 * 32 + lane];
    uint2 v3 = A4[(size_t)s3 * 32 + lane];
    acc_u2(acc, v0); acc_u2(acc, v1); acc_u2(acc, v2); acc_u2(acc, v3);
  }
  for (; e < end; e++)
    acc_u2(acc, A4[(size_t)ssrc[e] * 32 + lane]);

  float dv = dinv[node];
  int col = lane * 4;
  float4 bb = *(const float4*)&b1[col];
  float h0 = fmaxf(acc.x * dv + bb.x, 0.f);
  float h1 = fmaxf(acc.y * dv + bb.y, 0.f);
  float h2 = fmaxf(acc.z * dv + bb.z, 0.f);
  float h3 = fmaxf(acc.w * dv + bb.w, 0.f);
  unsigned base = (unsigned)node * HIDC + (unsigned)col;
  float4 o;
  o.x = keep_bit(base)     ? 2.f * h0 : 0.f;
  o.y = keep_bit(base + 1) ? 2.f * h1 : 0.f;
  o.z = keep_bit(base + 2) ? 2.f * h2 : 0.f;
  o.w = keep_bit(base + 3) ? 2.f * h3 : 0.f;
  ((float4*)H)[(size_t)node * 32 + lane] = o;
}

// ---------------- agg2: quarter-wave/node bf16 gather + bias -> d_out -------
// 16 lanes x uint2 = full 128 B row (one cache line per edge).
__global__ __launch_bounds__(256)
void agg2(const bf16_t* __restrict__ A2b, const int* __restrict__ offs,
          const int* __restrict__ ssrc, const float* __restrict__ dinv,
          const float* __restrict__ b2, float* __restrict__ out) {
  int node = (blockIdx.x * 256 + threadIdx.x) >> 4;
  int lane = threadIdx.x & 15;
  if (node >= NN) return;

  const uint2* A4 = (const uint2*)A2b;   // 16 uint2 per row
  float4 acc = make_float4(0.f, 0.f, 0.f, 0.f);
  acc_u2(acc, A4[(size_t)node * 16 + lane]);
  int e = offs[node], end = offs[node + 1];
  for (; e + 3 < end; e += 4) {
    int s0 = ssrc[e], s1 = ssrc[e+1], s2 = ssrc[e+2], s3 = ssrc[e+3];
    uint2 v0 = A4[(size_t)s0 * 16 + lane];
    uint2 v1 = A4[(size_t)s1 * 16 + lane];
    uint2 v2 = A4[(size_t)s2 * 16 + lane];
    uint2 v3 = A4[(size_t)s3 * 16 + lane];
    acc_u2(acc, v0); acc_u2(acc, v1); acc_u2(acc, v2); acc_u2(acc, v3);
  }
  for (; e < end; e++)
    acc_u2(acc, A4[(size_t)ssrc[e] * 16 + lane]);

  float dv = dinv[node];
  float4 bb = *(const float4*)&b2[lane * 4];
  ((float4*)out)[(size_t)node * 16 + lane] =
    make_float4(acc.x*dv + bb.x, acc.y*dv + bb.y, acc.z*dv + bb.z, acc.w*dv + bb.w);
}

// ---------------------------------------------------------------------------
extern "C" void kernel_launch(void* const* d_in, const int* in_sizes, int n_in,
                              void* d_out, int out_size, void* d_ws, size_t ws_size,
                              hipStream_t stream) {
  const float* x  = (const float*)d_in[0];
  const float* W1 = (const float*)d_in[1];
  const float* b1 = (const float*)d_in[2];
  const float* W2 = (const float*)d_in[3];
  const float* b2 = (const float*)d_in[4];
  const void*  ei = d_in[5];
  float* out = (float*)d_out;

  int*    flag   = (int*)d_ws;           // 64
  int*    deg    = flag + 64;            // 50048
  int*    offs   = deg + 50048;          // 50056
  int*    cursor = offs + 50056;         // 50048
  int*    ssrc   = cursor + 50048;       // 600000
  int*    bsum   = ssrc + NE;            // 256
  int*    boff   = bsum + 256;           // 256
  float*  dinv   = (float*)(boff + 256); // 50048
  bf16_t* A1b    = (bf16_t*)(dinv + 50048);       // 6.4M bf16 (3.2M int)
  float*  H      = (float*)(A1b + 6400000);       // 6.4M float
  bf16_t* A2b    = (bf16_t*)(H + 6400000);        // 3.2M bf16

  // 0. dtype + degree
  detect_edge_dtype<<<1, 256, 0, stream>>>((const unsigned*)ei, flag);
  zero_int<<<(NN + 255) / 256, 256, 0, stream>>>(deg, NN);
  count_deg_raw<<<(NE + 255) / 256, 256, 0, stream>>>(ei, flag, deg);

  // 1. hierarchical scan -> offs/cursor (+ dinv fused); CSR bucket
  scan_a<<<NB, 256, 0, stream>>>(deg, bsum, dinv);
  scan_b<<<1, 256, 0, stream>>>(bsum, boff, offs);
  scan_c<<<NB, 256, 0, stream>>>(deg, boff, offs, cursor);
  bucket_raw<<<(NE + 255) / 256, 256, 0, stream>>>(ei, flag, cursor, ssrc);

  // 2. layer 1
  gemm_scale_bf<INC, HIDC><<<dim3((NN + 31) / 32, 2), 256, 0, stream>>>(x, W1, dinv, A1b, NN);
  agg1<<<(NN * 32 + 255) / 256, 256, 0, stream>>>(A1b, offs, ssrc, dinv, b1, H);

  // 3. layer 2
  gemm_scale_bf<HIDC, OUTC><<<dim3((NN + 31) / 32, 1), 256, 0, stream>>>(H, W2, dinv, A2b, NN);
  agg2<<<(NN * 16 + 255) / 256, 256, 0, stream>>>(A2b, offs, ssrc, dinv, b2, out);
}

// Round 11
// 261.815 us; speedup vs baseline: 1.5070x; 1.0107x over previous
//
#include <hip/hip_runtime.h>

// GCN_72988674228318: 2-layer GCN on MI355X. R11:
//  - gemm: pad xs LDS stride (K+4) killing 4-way bank conflicts (3.2M -> ~0),
//    retile to 64x64 (RPT=4) so inner loop is FMA-bound not LDS-bound.
//  - preproc: zero via hipMemsetAsync; scan_b fused into scan_c.

#define NN      50000
#define INC     128
#define HIDC    128
#define OUTC    64
#define NE      600000
#define NB      ((NN + 255) / 256)   // 196 scan blocks

typedef unsigned short bf16_t;

__device__ __forceinline__ unsigned short f2bf(float f) {
  unsigned u = __float_as_uint(f);
  u += 0x7fffu + ((u >> 16) & 1u);   // round to nearest even
  return (unsigned short)(u >> 16);
}

// ---------------- Threefry-2x32, key = (0, 42); partitionable path ---------
__device__ __forceinline__ void tf_round(unsigned &x0, unsigned &x1, int r) {
  x0 += x1;
  x1 = (x1 << r) | (x1 >> (32 - r));
  x1 ^= x0;
}

__device__ __forceinline__ void threefry_0_42(unsigned &x0, unsigned &x1) {
  const unsigned ks0 = 0u, ks1 = 42u, ks2 = 0x1BD11BDAu ^ 42u;
  x0 += ks0; x1 += ks1;
  tf_round(x0,x1,13); tf_round(x0,x1,15); tf_round(x0,x1,26); tf_round(x0,x1, 6);
  x0 += ks1; x1 += ks2 + 1u;
  tf_round(x0,x1,17); tf_round(x0,x1,29); tf_round(x0,x1,16); tf_round(x0,x1,24);
  x0 += ks2; x1 += ks0 + 2u;
  tf_round(x0,x1,13); tf_round(x0,x1,15); tf_round(x0,x1,26); tf_round(x0,x1, 6);
  x0 += ks0; x1 += ks1 + 3u;
  tf_round(x0,x1,17); tf_round(x0,x1,29); tf_round(x0,x1,16); tf_round(x0,x1,24);
  x0 += ks1; x1 += ks2 + 4u;
  tf_round(x0,x1,13); tf_round(x0,x1,15); tf_round(x0,x1,26); tf_round(x0,x1, 6);
  x0 += ks2; x1 += ks0 + 5u;
}

__device__ __forceinline__ bool keep_bit(unsigned idx) {
  unsigned x0 = 0u, x1 = idx;
  threefry_0_42(x0, x1);
  return ((x0 ^ x1) & 0x80000000u) == 0u;
}

// ---------------- edge dtype detect -----------------------------------------
__global__ void detect_edge_dtype(const unsigned* __restrict__ w, int* __restrict__ flag) {
  __shared__ unsigned acc[256];
  unsigned v = 0;
  for (int i = threadIdx.x; i < 2048; i += 256) v |= w[2 * i + 1];
  acc[threadIdx.x] = v;
  __syncthreads();
  for (int s = 128; s > 0; s >>= 1) {
    if (threadIdx.x < s) acc[threadIdx.x] |= acc[threadIdx.x + s];
    __syncthreads();
  }
  if (threadIdx.x == 0) *flag = (acc[0] == 0u) ? 1 : 0;   // 1 => int64
}

__global__ __launch_bounds__(256)
void count_deg_raw(const void* __restrict__ ei, const int* __restrict__ flag,
                   int* __restrict__ deg) {
  int t = blockIdx.x * 256 + threadIdx.x;
  if (t >= NE) return;
  int d = (*flag) ? (int)((const long long*)ei)[NE + t]
                  : ((const int*)ei)[NE + t];
  atomicAdd(&deg[d], 1);
}

// ---------------- scan stage a: block sums + dinv ---------------------------
__global__ __launch_bounds__(256)
void scan_a(const int* __restrict__ deg, int* __restrict__ bsum,
            float* __restrict__ dinv) {
  __shared__ int red[256];
  int t = threadIdx.x, idx = blockIdx.x * 256 + t;
  int d = (idx < NN) ? deg[idx] : 0;
  if (idx < NN) dinv[idx] = 1.0f / sqrtf((float)(d + 1));
  red[t] = d;
  __syncthreads();
  for (int s = 128; s > 0; s >>= 1) {
    if (t < s) red[t] += red[t + s];
    __syncthreads();
  }
  if (t == 0) bsum[blockIdx.x] = red[0];
}

// ---------------- scan stage c (fused b): offs + cursor ---------------------
// Every block redundantly scans the NB block sums in LDS (cheap), then does
// its local exclusive scan.
__global__ __launch_bounds__(256)
void scan_c(const int* __restrict__ deg, const int* __restrict__ bsum,
            int* __restrict__ offs, int* __restrict__ cursor) {
  __shared__ int gs[256];   // global block-sum scan (inclusive)
  __shared__ int ls[256];   // local scan
  int t = threadIdx.x, idx = blockIdx.x * 256 + t;

  int bv = (t < NB) ? bsum[t] : 0;
  gs[t] = bv;
  int d = (idx < NN) ? deg[idx] : 0;
  ls[t] = d;
  __syncthreads();
  for (int off = 1; off < 256; off <<= 1) {
    int g = (t >= off) ? gs[t - off] : 0;
    int l = (t >= off) ? ls[t - off] : 0;
    __syncthreads();
    gs[t] += g;
    ls[t] += l;
    __syncthreads();
  }
  int boff = (blockIdx.x == 0) ? 0 : gs[blockIdx.x - 1];
  if (idx < NN) {
    int o = boff + ls[t] - d;
    offs[idx] = o;
    cursor[idx] = o;
  }
  if (blockIdx.x == 0 && t == 255) offs[NN] = gs[NB - 1];   // == NE
}

__global__ __launch_bounds__(256)
void bucket_raw(const void* __restrict__ ei, const int* __restrict__ flag,
                int* __restrict__ cursor, int* __restrict__ ssrc) {
  int t = blockIdx.x * 256 + threadIdx.x;
  if (t >= NE) return;
  int s, d;
  if (*flag) {
    s = (int)((const long long*)ei)[t];
    d = (int)((const long long*)ei)[NE + t];
  } else {
    s = ((const int*)ei)[t];
    d = ((const int*)ei)[NE + t];
  }
  int pos = atomicAdd(&cursor[d], 1);
  ssrc[pos] = s;
}

// ---------------- GEMM: Ab = bf16((X @ W) * dinv[row]), 64x64 tiles ---------
// grid: (ceil(n/64), C/64). 256 thr, RPT=4. xs padded to K+4 (bank rotate).
// LDS = 32 KB (ws) + 33.8 KB (xs) -> 2 blocks/CU.
template<int K, int C>
__global__ __launch_bounds__(256, 2)
void gemm_scale_bf(const float* __restrict__ X, const float* __restrict__ W,
                   const float* __restrict__ dinv, bf16_t* __restrict__ Ab, int n) {
  constexpr int CT = 64;
  constexpr int KP = K + 4;
  __shared__ float ws[K * CT];
  __shared__ float xs[64 * KP];
  const int tid = threadIdx.x;
  const int rowbase = blockIdx.x * 64;
  const int c0 = blockIdx.y * CT;

  for (int i = tid * 4; i < K * CT; i += 256 * 4) {
    int k = i / CT, c = i % CT;
    *(float4*)&ws[i] = *(const float4*)&W[(size_t)k * C + c0 + c];
  }
  for (int i = tid; i < 64 * (K / 4); i += 256) {
    int r = i / (K / 4), k4 = i % (K / 4);
    int row = rowbase + r;
    float4 v = make_float4(0.f, 0.f, 0.f, 0.f);
    if (row < n) v = *(const float4*)&X[(size_t)row * K + k4 * 4];
    *(float4*)&xs[r * KP + k4 * 4] = v;
  }
  __syncthreads();

  constexpr int CG  = CT / 4;   // 16 col groups
  constexpr int RPT = 4;        // rows per thread
  const int colq = tid % CG;
  const int rowq = tid / CG;    // 0..15

  float acc[RPT][4];
#pragma unroll
  for (int r = 0; r < RPT; r++)
#pragma unroll
    for (int c = 0; c < 4; c++) acc[r][c] = 0.f;

#pragma unroll 2
  for (int k0 = 0; k0 < K; k0 += 4) {
    float4 wv[4];
#pragma unroll
    for (int j = 0; j < 4; j++)
      wv[j] = *(float4*)&ws[(k0 + j) * CT + colq * 4];
#pragma unroll
    for (int r = 0; r < RPT; r++) {
      float4 xv = *(float4*)&xs[(rowq * RPT + r) * KP + k0];
      acc[r][0] += xv.x*wv[0].x + xv.y*wv[1].x + xv.z*wv[2].x + xv.w*wv[3].x;
      acc[r][1] += xv.x*wv[0].y + xv.y*wv[1].y + xv.z*wv[2].y + xv.w*wv[3].y;
      acc[r][2] += xv.x*wv[0].z + xv.y*wv[1].z + xv.z*wv[2].z + xv.w*wv[3].z;
      acc[r][3] += xv.x*wv[0].w + xv.y*wv[1].w + xv.z*wv[2].w + xv.w*wv[3].w;
    }
  }

#pragma unroll
  for (int r = 0; r < RPT; r++) {
    int row = rowbase + rowq * RPT + r;
    if (row < n) {
      float s = dinv[row];
      ushort4 o;
      o.x = f2bf(acc[r][0] * s);
      o.y = f2bf(acc[r][1] * s);
      o.z = f2bf(acc[r][2] * s);
      o.w = f2bf(acc[r][3] * s);
      *(ushort4*)&Ab[(size_t)row * C + c0 + colq * 4] = o;
    }
  }
}

__device__ __forceinline__ void acc_u2(float4 &a, uint2 v) {
  a.x += __uint_as_float(v.x << 16);
  a.y += __uint_as_float(v.x & 0xffff0000u);
  a.z += __uint_as_float(v.y << 16);
  a.w += __uint_as_float(v.y & 0xffff0000u);
}

// ---------------- agg1: half-wave/node bf16 gather + bias/relu/dropout ------
__global__ __launch_bounds__(256)
void agg1(const bf16_t* __restrict__ A1b, const int* __restrict__ offs,
          const int* __restrict__ ssrc, const float* __restrict__ dinv,
          const float* __restrict__ b1, float* __restrict__ H) {
  int node = (blockIdx.x * 256 + threadIdx.x) >> 5;
  int lane = threadIdx.x & 31;
  if (node >= NN) return;

  const uint2* A4 = (const uint2*)A1b;   // 4 bf16 per uint2; 32 per row
  float4 acc = make_float4(0.f, 0.f, 0.f, 0.f);
  acc_u2(acc, A4[(size_t)node * 32 + lane]);   // self-loop
  int e = offs[node], end = offs[node + 1];
  for (; e + 3 < end; e += 4) {
    int s0 = ssrc[e], s1 = ssrc[e+1], s2 = ssrc[e+2], s3 = ssrc[e+3];
    uint2 v0 = A4[(size_t)s0 * 32 + lane];
    uint2 v1 = A4[(size_t)s1 * 32 + lane];
    uint2 v2 = A4[(size_t)s2 * 32 + lane];
    uint2 v3 = A4[(size_t)s3 * 32 + lane];
    acc_u2(acc, v0); acc_u2(acc, v1); acc_u2(acc, v2); acc_u2(acc, v3);
  }
  for (; e < end; e++)
    acc_u2(acc, A4[(size_t)ssrc[e] * 32 + lane]);

  float dv = dinv[node];
  int col = lane * 4;
  float4 bb = *(const float4*)&b1[col];
  float h0 = fmaxf(acc.x * dv + bb.x, 0.f);
  float h1 = fmaxf(acc.y * dv + bb.y, 0.f);
  float h2 = fmaxf(acc.z * dv + bb.z, 0.f);
  float h3 = fmaxf(acc.w * dv + bb.w, 0.f);
  unsigned base = (unsigned)node * HIDC + (unsigned)col;
  float4 o;
  o.x = keep_bit(base)     ? 2.f * h0 : 0.f;
  o.y = keep_bit(base + 1) ? 2.f * h1 : 0.f;
  o.z = keep_bit(base + 2) ? 2.f * h2 : 0.f;
  o.w = keep_bit(base + 3) ? 2.f * h3 : 0.f;
  ((float4*)H)[(size_t)node * 32 + lane] = o;
}

// ---------------- agg2: quarter-wave/node bf16 gather + bias -> d_out -------
__global__ __launch_bounds__(256)
void agg2(const bf16_t* __restrict__ A2b, const int* __restrict__ offs,
          const int* __restrict__ ssrc, const float* __restrict__ dinv,
          const float* __restrict__ b2, float* __restrict__ out) {
  int node = (blockIdx.x * 256 + threadIdx.x) >> 4;
  int lane = threadIdx.x & 15;
  if (node >= NN) return;

  const uint2* A4 = (const uint2*)A2b;   // 16 uint2 per row
  float4 acc = make_float4(0.f, 0.f, 0.f, 0.f);
  acc_u2(acc, A4[(size_t)node * 16 + lane]);
  int e = offs[node], end = offs[node + 1];
  for (; e + 3 < end; e += 4) {
    int s0 = ssrc[e], s1 = ssrc[e+1], s2 = ssrc[e+2], s3 = ssrc[e+3];
    uint2 v0 = A4[(size_t)s0 * 16 + lane];
    uint2 v1 = A4[(size_t)s1 * 16 + lane];
    uint2 v2 = A4[(size_t)s2 * 16 + lane];
    uint2 v3 = A4[(size_t)s3 * 16 + lane];
    acc_u2(acc, v0); acc_u2(acc, v1); acc_u2(acc, v2); acc_u2(acc, v3);
  }
  for (; e < end; e++)
    acc_u2(acc, A4[(size_t)ssrc[e] * 16 + lane]);

  float dv = dinv[node];
  float4 bb = *(const float4*)&b2[lane * 4];
  ((float4*)out)[(size_t)node * 16 + lane] =
    make_float4(acc.x*dv + bb.x, acc.y*dv + bb.y, acc.z*dv + bb.z, acc.w*dv + bb.w);
}

// ---------------------------------------------------------------------------
extern "C" void kernel_launch(void* const* d_in, const int* in_sizes, int n_in,
                              void* d_out, int out_size, void* d_ws, size_t ws_size,
                              hipStream_t stream) {
  const float* x  = (const float*)d_in[0];
  const float* W1 = (const float*)d_in[1];
  const float* b1 = (const float*)d_in[2];
  const float* W2 = (const float*)d_in[3];
  const float* b2 = (const float*)d_in[4];
  const void*  ei = d_in[5];
  float* out = (float*)d_out;

  int*    flag   = (int*)d_ws;           // 64
  int*    deg    = flag + 64;            // 50048
  int*    offs   = deg + 50048;          // 50056
  int*    cursor = offs + 50056;         // 50048
  int*    ssrc   = cursor + 50048;       // 600000
  int*    bsum   = ssrc + NE;            // 256
  float*  dinv   = (float*)(bsum + 256); // 50048
  bf16_t* A1b    = (bf16_t*)(dinv + 50048);       // 6.4M bf16
  float*  H      = (float*)(A1b + 6400000);       // 6.4M float
  bf16_t* A2b    = (bf16_t*)(H + 6400000);        // 3.2M bf16

  // 0. dtype + degree (deg zeroed via async memset — graph-capturable)
  detect_edge_dtype<<<1, 256, 0, stream>>>((const unsigned*)ei, flag);
  hipMemsetAsync(deg, 0, NN * sizeof(int), stream);
  count_deg_raw<<<(NE + 255) / 256, 256, 0, stream>>>(ei, flag, deg);

  // 1. scan (a: sums+dinv, c: fused global+local) ; CSR bucket
  scan_a<<<NB, 256, 0, stream>>>(deg, bsum, dinv);
  scan_c<<<NB, 256, 0, stream>>>(deg, bsum, offs, cursor);
  bucket_raw<<<(NE + 255) / 256, 256, 0, stream>>>(ei, flag, cursor, ssrc);

  const int rtiles = (NN + 63) / 64;   // 782

  // 2. layer 1
  gemm_scale_bf<INC, HIDC><<<dim3(rtiles, 2), 256, 0, stream>>>(x, W1, dinv, A1b, NN);
  agg1<<<(NN * 32 + 255) / 256, 256, 0, stream>>>(A1b, offs, ssrc, dinv, b1, H);

  // 3. layer 2
  gemm_scale_bf<HIDC, OUTC><<<dim3(rtiles, 1), 256, 0, stream>>>(H, W2, dinv, A2b, NN);
  agg2<<<(NN * 16 + 255) / 256, 256, 0, stream>>>(A2b, offs, ssrc, dinv, b2, out);
}

// Round 12
// 228.714 us; speedup vs baseline: 1.7251x; 1.1447x over previous
//
#include <hip/hip_runtime.h>

// GCN_72988674228318: 2-layer GCN on MI355X. R12: replace vector GEMMs
// (LDS-BW bound, 47+22 us) with MFMA bf16 GEMMs (v_mfma_f32_16x16x32_bf16).
// X/W converted to bf16 during LDS staging; H now stored bf16 by agg1.
// Fragment layouts per verified guide: A[m=lane&15][k=quad*8+j] (m120),
// B from W^T, C/D col=lane&15,row=quad*4+reg (m89/m91).

#define NN      50000
#define INC     128
#define HIDC    128
#define OUTC    64
#define NE      600000
#define NB      ((NN + 255) / 256)   // 196 scan blocks

typedef unsigned short bf16_t;
typedef short bf16x8 __attribute__((ext_vector_type(8)));
typedef float f32x4  __attribute__((ext_vector_type(4)));

__device__ __forceinline__ unsigned short f2bf(float f) {
  unsigned u = __float_as_uint(f);
  u += 0x7fffu + ((u >> 16) & 1u);   // round to nearest even
  return (unsigned short)(u >> 16);
}

// ---------------- Threefry-2x32, key = (0, 42); partitionable path ---------
__device__ __forceinline__ void tf_round(unsigned &x0, unsigned &x1, int r) {
  x0 += x1;
  x1 = (x1 << r) | (x1 >> (32 - r));
  x1 ^= x0;
}

__device__ __forceinline__ void threefry_0_42(unsigned &x0, unsigned &x1) {
  const unsigned ks0 = 0u, ks1 = 42u, ks2 = 0x1BD11BDAu ^ 42u;
  x0 += ks0; x1 += ks1;
  tf_round(x0,x1,13); tf_round(x0,x1,15); tf_round(x0,x1,26); tf_round(x0,x1, 6);
  x0 += ks1; x1 += ks2 + 1u;
  tf_round(x0,x1,17); tf_round(x0,x1,29); tf_round(x0,x1,16); tf_round(x0,x1,24);
  x0 += ks2; x1 += ks0 + 2u;
  tf_round(x0,x1,13); tf_round(x0,x1,15); tf_round(x0,x1,26); tf_round(x0,x1, 6);
  x0 += ks0; x1 += ks1 + 3u;
  tf_round(x0,x1,17); tf_round(x0,x1,29); tf_round(x0,x1,16); tf_round(x0,x1,24);
  x0 += ks1; x1 += ks2 + 4u;
  tf_round(x0,x1,13); tf_round(x0,x1,15); tf_round(x0,x1,26); tf_round(x0,x1, 6);
  x0 += ks2; x1 += ks0 + 5u;
}

__device__ __forceinline__ bool keep_bit(unsigned idx) {
  unsigned x0 = 0u, x1 = idx;
  threefry_0_42(x0, x1);
  return ((x0 ^ x1) & 0x80000000u) == 0u;
}

// ---------------- edge dtype detect -----------------------------------------
__global__ void detect_edge_dtype(const unsigned* __restrict__ w, int* __restrict__ flag) {
  __shared__ unsigned acc[256];
  unsigned v = 0;
  for (int i = threadIdx.x; i < 2048; i += 256) v |= w[2 * i + 1];
  acc[threadIdx.x] = v;
  __syncthreads();
  for (int s = 128; s > 0; s >>= 1) {
    if (threadIdx.x < s) acc[threadIdx.x] |= acc[threadIdx.x + s];
    __syncthreads();
  }
  if (threadIdx.x == 0) *flag = (acc[0] == 0u) ? 1 : 0;   // 1 => int64
}

__global__ __launch_bounds__(256)
void count_deg_raw(const void* __restrict__ ei, const int* __restrict__ flag,
                   int* __restrict__ deg) {
  int t = blockIdx.x * 256 + threadIdx.x;
  if (t >= NE) return;
  int d = (*flag) ? (int)((const long long*)ei)[NE + t]
                  : ((const int*)ei)[NE + t];
  atomicAdd(&deg[d], 1);
}

// ---------------- scan stage a: block sums + dinv ---------------------------
__global__ __launch_bounds__(256)
void scan_a(const int* __restrict__ deg, int* __restrict__ bsum,
            float* __restrict__ dinv) {
  __shared__ int red[256];
  int t = threadIdx.x, idx = blockIdx.x * 256 + t;
  int d = (idx < NN) ? deg[idx] : 0;
  if (idx < NN) dinv[idx] = 1.0f / sqrtf((float)(d + 1));
  red[t] = d;
  __syncthreads();
  for (int s = 128; s > 0; s >>= 1) {
    if (t < s) red[t] += red[t + s];
    __syncthreads();
  }
  if (t == 0) bsum[blockIdx.x] = red[0];
}

// ---------------- scan stage c (fused b): offs + cursor ---------------------
__global__ __launch_bounds__(256)
void scan_c(const int* __restrict__ deg, const int* __restrict__ bsum,
            int* __restrict__ offs, int* __restrict__ cursor) {
  __shared__ int gs[256];
  __shared__ int ls[256];
  int t = threadIdx.x, idx = blockIdx.x * 256 + t;

  int bv = (t < NB) ? bsum[t] : 0;
  gs[t] = bv;
  int d = (idx < NN) ? deg[idx] : 0;
  ls[t] = d;
  __syncthreads();
  for (int off = 1; off < 256; off <<= 1) {
    int g = (t >= off) ? gs[t - off] : 0;
    int l = (t >= off) ? ls[t - off] : 0;
    __syncthreads();
    gs[t] += g;
    ls[t] += l;
    __syncthreads();
  }
  int boff = (blockIdx.x == 0) ? 0 : gs[blockIdx.x - 1];
  if (idx < NN) {
    int o = boff + ls[t] - d;
    offs[idx] = o;
    cursor[idx] = o;
  }
  if (blockIdx.x == 0 && t == 255) offs[NN] = gs[NB - 1];
}

__global__ __launch_bounds__(256)
void bucket_raw(const void* __restrict__ ei, const int* __restrict__ flag,
                int* __restrict__ cursor, int* __restrict__ ssrc) {
  int t = blockIdx.x * 256 + threadIdx.x;
  if (t >= NE) return;
  int s, d;
  if (*flag) {
    s = (int)((const long long*)ei)[t];
    d = (int)((const long long*)ei)[NE + t];
  } else {
    s = ((const int*)ei)[t];
    d = ((const int*)ei)[NE + t];
  }
  int pos = atomicAdd(&cursor[d], 1);
  ssrc[pos] = s;
}

// ---------------- MFMA GEMM: Ab = bf16((X @ W) * dinv[row]) -----------------
// 64 rows/block (4 waves x 16), all C cols per block. K = 128.
// LDS: xs [64][KS] bf16, wsT [C][KS] bf16 (W transposed), KS=136 (16B-aligned
// stride, bank-uniform). Per wave k0-step: 1 a-read + (C/16) b-reads (b128),
// C/16 MFMAs.
template<int C, bool IN_BF16>
__global__ __launch_bounds__(256, 3)
void gemm_mfma(const void* __restrict__ Xv, const float* __restrict__ W,
               const float* __restrict__ dinv, bf16_t* __restrict__ Ab, int n) {
  constexpr int K  = 128;
  constexpr int KS = 136;
  constexpr int CT16 = C / 16;
  __shared__ bf16_t xs[64 * KS];
  __shared__ bf16_t wsT[C * KS];

  const int tid = threadIdx.x;
  const int rb  = blockIdx.x * 64;

  // stage W^T (fp32 -> bf16): chunk i = (n, kc): 8 coalesced loads, 1 b128 write
  for (int i = tid; i < C * (K / 8); i += 256) {
    int nn = i % C, kc = i / C;
    ushort4 lo, hi;
    lo.x = f2bf(W[(size_t)(kc * 8 + 0) * C + nn]);
    lo.y = f2bf(W[(size_t)(kc * 8 + 1) * C + nn]);
    lo.z = f2bf(W[(size_t)(kc * 8 + 2) * C + nn]);
    lo.w = f2bf(W[(size_t)(kc * 8 + 3) * C + nn]);
    hi.x = f2bf(W[(size_t)(kc * 8 + 4) * C + nn]);
    hi.y = f2bf(W[(size_t)(kc * 8 + 5) * C + nn]);
    hi.z = f2bf(W[(size_t)(kc * 8 + 6) * C + nn]);
    hi.w = f2bf(W[(size_t)(kc * 8 + 7) * C + nn]);
    *(ushort4*)&wsT[nn * KS + kc * 8]     = lo;
    *(ushort4*)&wsT[nn * KS + kc * 8 + 4] = hi;
  }
  // stage X rows (fp32->bf16 or bf16 copy)
  for (int i = tid; i < 64 * (K / 4); i += 256) {
    int r = i >> 5, kq = i & 31;
    int row = rb + r;
    ushort4 o = make_ushort4(0, 0, 0, 0);
    if (row < n) {
      if (IN_BF16) {
        o = *(const ushort4*)((const bf16_t*)Xv + (size_t)row * K + kq * 4);
      } else {
        float4 v = *(const float4*)((const float*)Xv + (size_t)row * K + kq * 4);
        o.x = f2bf(v.x); o.y = f2bf(v.y); o.z = f2bf(v.z); o.w = f2bf(v.w);
      }
    }
    *(ushort4*)&xs[r * KS + kq * 4] = o;
  }
  __syncthreads();

  const int wv   = tid >> 6;
  const int lane = tid & 63;
  const int m    = lane & 15;    // row within wave tile / col within ctile
  const int q    = lane >> 4;    // quad

  f32x4 acc[CT16];
#pragma unroll
  for (int c = 0; c < CT16; c++) acc[c] = (f32x4){0.f, 0.f, 0.f, 0.f};

#pragma unroll
  for (int k0 = 0; k0 < K; k0 += 32) {
    bf16x8 a = *(bf16x8*)&xs[(wv * 16 + m) * KS + k0 + q * 8];
#pragma unroll
    for (int c = 0; c < CT16; c++) {
      bf16x8 b = *(bf16x8*)&wsT[(c * 16 + m) * KS + k0 + q * 8];
      acc[c] = __builtin_amdgcn_mfma_f32_16x16x32_bf16(a, b, acc[c], 0, 0, 0);
    }
  }

  // epilogue: D[row=rb+wv*16+q*4+r][col=c*16+m] -> bf16 * dinv[row]
  const int rowq = rb + wv * 16 + q * 4;
#pragma unroll
  for (int r = 0; r < 4; r++) {
    int row = rowq + r;
    if (row < n) {
      float dv = dinv[row];
#pragma unroll
      for (int c = 0; c < CT16; c++)
        Ab[(size_t)row * C + c * 16 + m] = f2bf(acc[c][r] * dv);
    }
  }
}

__device__ __forceinline__ void acc_u2(float4 &a, uint2 v) {
  a.x += __uint_as_float(v.x << 16);
  a.y += __uint_as_float(v.x & 0xffff0000u);
  a.z += __uint_as_float(v.y << 16);
  a.w += __uint_as_float(v.y & 0xffff0000u);
}

// ---------------- agg1: half-wave/node bf16 gather -> Hb (bf16) -------------
__global__ __launch_bounds__(256)
void agg1(const bf16_t* __restrict__ A1b, const int* __restrict__ offs,
          const int* __restrict__ ssrc, const float* __restrict__ dinv,
          const float* __restrict__ b1, bf16_t* __restrict__ Hb) {
  int node = (blockIdx.x * 256 + threadIdx.x) >> 5;
  int lane = threadIdx.x & 31;
  if (node >= NN) return;

  const uint2* A4 = (const uint2*)A1b;   // 4 bf16 per uint2; 32 per row
  float4 acc = make_float4(0.f, 0.f, 0.f, 0.f);
  acc_u2(acc, A4[(size_t)node * 32 + lane]);   // self-loop
  int e = offs[node], end = offs[node + 1];
  for (; e + 3 < end; e += 4) {
    int s0 = ssrc[e], s1 = ssrc[e+1], s2 = ssrc[e+2], s3 = ssrc[e+3];
    uint2 v0 = A4[(size_t)s0 * 32 + lane];
    uint2 v1 = A4[(size_t)s1 * 32 + lane];
    uint2 v2 = A4[(size_t)s2 * 32 + lane];
    uint2 v3 = A4[(size_t)s3 * 32 + lane];
    acc_u2(acc, v0); acc_u2(acc, v1); acc_u2(acc, v2); acc_u2(acc, v3);
  }
  for (; e < end; e++)
    acc_u2(acc, A4[(size_t)ssrc[e] * 32 + lane]);

  float dv = dinv[node];
  int col = lane * 4;
  float4 bb = *(const float4*)&b1[col];
  float h0 = fmaxf(acc.x * dv + bb.x, 0.f);
  float h1 = fmaxf(acc.y * dv + bb.y, 0.f);
  float h2 = fmaxf(acc.z * dv + bb.z, 0.f);
  float h3 = fmaxf(acc.w * dv + bb.w, 0.f);
  unsigned base = (unsigned)node * HIDC + (unsigned)col;
  ushort4 o;
  o.x = keep_bit(base)     ? f2bf(2.f * h0) : 0;
  o.y = keep_bit(base + 1) ? f2bf(2.f * h1) : 0;
  o.z = keep_bit(base + 2) ? f2bf(2.f * h2) : 0;
  o.w = keep_bit(base + 3) ? f2bf(2.f * h3) : 0;
  ((ushort4*)Hb)[(size_t)node * 32 + lane] = o;
}

// ---------------- agg2: quarter-wave/node bf16 gather + bias -> d_out -------
__global__ __launch_bounds__(256)
void agg2(const bf16_t* __restrict__ A2b, const int* __restrict__ offs,
          const int* __restrict__ ssrc, const float* __restrict__ dinv,
          const float* __restrict__ b2, float* __restrict__ out) {
  int node = (blockIdx.x * 256 + threadIdx.x) >> 4;
  int lane = threadIdx.x & 15;
  if (node >= NN) return;

  const uint2* A4 = (const uint2*)A2b;   // 16 uint2 per row
  float4 acc = make_float4(0.f, 0.f, 0.f, 0.f);
  acc_u2(acc, A4[(size_t)node * 16 + lane]);
  int e = offs[node], end = offs[node + 1];
  for (; e + 3 < end; e += 4) {
    int s0 = ssrc[e], s1 = ssrc[e+1], s2 = ssrc[e+2], s3 = ssrc[e+3];
    uint2 v0 = A4[(size_t)s0 * 16 + lane];
    uint2 v1 = A4[(size_t)s1 * 16 + lane];
    uint2 v2 = A4[(size_t)s2 * 16 + lane];
    uint2 v3 = A4[(size_t)s3 * 16 + lane];
    acc_u2(acc, v0); acc_u2(acc, v1); acc_u2(acc, v2); acc_u2(acc, v3);
  }
  for (; e < end; e++)
    acc_u2(acc, A4[(size_t)ssrc[e] * 16 + lane]);

  float dv = dinv[node];
  float4 bb = *(const float4*)&b2[lane * 4];
  ((float4*)out)[(size_t)node * 16 + lane] =
    make_float4(acc.x*dv + bb.x, acc.y*dv + bb.y, acc.z*dv + bb.z, acc.w*dv + bb.w);
}

// ---------------------------------------------------------------------------
extern "C" void kernel_launch(void* const* d_in, const int* in_sizes, int n_in,
                              void* d_out, int out_size, void* d_ws, size_t ws_size,
                              hipStream_t stream) {
  const float* x  = (const float*)d_in[0];
  const float* W1 = (const float*)d_in[1];
  const float* b1 = (const float*)d_in[2];
  const float* W2 = (const float*)d_in[3];
  const float* b2 = (const float*)d_in[4];
  const void*  ei = d_in[5];
  float* out = (float*)d_out;

  int*    flag   = (int*)d_ws;           // 64
  int*    deg    = flag + 64;            // 50048
  int*    offs   = deg + 50048;          // 50056
  int*    cursor = offs + 50056;         // 50048
  int*    ssrc   = cursor + 50048;       // 600000
  int*    bsum   = ssrc + NE;            // 256
  float*  dinv   = (float*)(bsum + 256); // 50048
  bf16_t* A1b    = (bf16_t*)(dinv + 50048);       // 6.4M bf16
  bf16_t* Hb     = A1b + 6400000;                 // 6.4M bf16
  bf16_t* A2b    = Hb + 6400000;                  // 3.2M bf16

  // 0. dtype + degree
  detect_edge_dtype<<<1, 256, 0, stream>>>((const unsigned*)ei, flag);
  hipMemsetAsync(deg, 0, NN * sizeof(int), stream);
  count_deg_raw<<<(NE + 255) / 256, 256, 0, stream>>>(ei, flag, deg);

  // 1. scan; CSR bucket
  scan_a<<<NB, 256, 0, stream>>>(deg, bsum, dinv);
  scan_c<<<NB, 256, 0, stream>>>(deg, bsum, offs, cursor);
  bucket_raw<<<(NE + 255) / 256, 256, 0, stream>>>(ei, flag, cursor, ssrc);

  const int rtiles = (NN + 63) / 64;   // 782

  // 2. layer 1: MFMA gemm (fp32 x -> bf16), gather+relu+dropout -> Hb (bf16)
  gemm_mfma<HIDC, false><<<rtiles, 256, 0, stream>>>(x, W1, dinv, A1b, NN);
  agg1<<<(NN * 32 + 255) / 256, 256, 0, stream>>>(A1b, offs, ssrc, dinv, b1, Hb);

  // 3. layer 2: MFMA gemm (bf16 Hb), gather + bias -> out
  gemm_mfma<OUTC, true><<<rtiles, 256, 0, stream>>>(Hb, W2, dinv, A2b, NN);
  agg2<<<(NN * 16 + 255) / 256, 256, 0, stream>>>(A2b, offs, ssrc, dinv, b2, out);
}